// Round 2
// baseline (498.276 us; speedup 1.0000x reference)
//
#include <hip/hip_runtime.h>

#define BS   32
#define SLEN 4096
#define EM   256
#define NROWS (BS * SLEN)  // 131072

// ---------------- ws layout (floats) ----------------
#define WS_WKT   0         // 65536  : wk transposed [j][e]
#define WS_EN    65536     // 131072 : raw energy (tanh(k)@we_k), no const/mask
#define WS_CONST 196608    // 16     : scalar energy_q + be
#define WS_W     196624    // 131072 : softmax weights
#define WS_PART  327696    // 524288 : wsum partials (32b x 16ch x 4g) x 256
// total ~852K floats = 3.3 MB

// ---- K0: transpose wk (EM x EM) -> wkT so GEMM B-staging is coalesced ----
__global__ __launch_bounds__(256) void k0_transpose(const float* __restrict__ wk,
                                                    float* __restrict__ wkT) {
  __shared__ float tile[32][33];
  int bx = blockIdx.x & 7;   // col tile
  int by = blockIdx.x >> 3;  // row tile
  int t = threadIdx.x & 31;
  int u = threadIdx.x >> 5;  // 0..7
#pragma unroll
  for (int p = 0; p < 4; ++p) {
    int r = u + p * 8;
    tile[r][t] = wk[(size_t)(by * 32 + r) * EM + bx * 32 + t];
  }
  __syncthreads();
#pragma unroll
  for (int p = 0; p < 4; ++p) {
    int r = u + p * 8;
    wkT[(size_t)(bx * 32 + r) * EM + by * 32 + t] = tile[t][r];
  }
}

// ---- K0b: scalar query path: C = tanh(relu(wq@w_query+bq)) . we_q + be ----
__global__ __launch_bounds__(256) void k0b_qscalar(const float* __restrict__ w_query,
                                                   const float* __restrict__ wq,
                                                   const float* __restrict__ bq,
                                                   const float* __restrict__ we,
                                                   const float* __restrict__ be,
                                                   float* __restrict__ outc) {
  int t = threadIdx.x;  // t = e
  float a = 0.f;
  const float* row = wq + (size_t)t * EM;
#pragma unroll 8
  for (int j = 0; j < EM; ++j) a = fmaf(row[j], w_query[j], a);
  a += bq[t];
  float v = we[t] * tanhf(fmaxf(a, 0.f));
#pragma unroll
  for (int off = 32; off >= 1; off >>= 1) v += __shfl_xor(v, off, 64);
  __shared__ float red[4];
  if ((t & 63) == 0) red[t >> 6] = v;
  __syncthreads();
  if (t == 0) outc[0] = red[0] + red[1] + red[2] + red[3] + be[0];
}

// ---- K1: energy[row] = sum_e we_k[e] * tanh(relu(X[row].wk[e] + bk[e])) ----
// Tile: 128 rows x 256 cols (all e), K-chunks of 32. 256 thr: 16x16 grid,
// each thread 8 rows x 16 cols. LDS XOR-swizzled (rows differing by 8 would
// otherwise alias banks; e-stride 16 floats would 8-way-conflict reads).
__global__ __launch_bounds__(256) void k1_energy(const float* __restrict__ X,
                                                 const float* __restrict__ wkT,
                                                 const float* __restrict__ bk,
                                                 const float* __restrict__ we,
                                                 float* __restrict__ energy) {
  __shared__ float As[128][32];
  __shared__ float Bs[32][256];
  const int tid = threadIdx.x;
  const int tx = tid & 15;    // col group (e0 = 16*tx)
  const int ty = tid >> 4;    // row group (r0 = 8*ty)
  const int row0 = blockIdx.x * 128;
  const int r0 = ty * 8;
  const int e0 = tx * 16;

  float acc[8][16];
#pragma unroll
  for (int i = 0; i < 8; ++i)
#pragma unroll
    for (int c = 0; c < 16; ++c) acc[i][c] = 0.f;

  // swizzled B read offsets (in floats), one per 4-col quad
  int bqoff[4];
#pragma unroll
  for (int qq = 0; qq < 4; ++qq) {
    int quad = tx * 4 + qq;
    bqoff[qq] = (quad ^ ((quad >> 3) & 7)) * 4;
  }
  const int sa_c4 = tid & 7;   // A stage: quad in 32-float row
  const int sa_rr = tid >> 3;  // A stage: row base (0..31)
  const int sb_c4 = tid & 63;  // B stage: quad in 256-float row
  const int sb_off = (sb_c4 ^ ((sb_c4 >> 3) & 7)) * 4;
  const int sb_j = tid >> 6;   // 0..3

  for (int k0 = 0; k0 < EM; k0 += 32) {
    // stage A tile (128x32), XOR-swizzle quad by (row>>3)&7
#pragma unroll
    for (int p = 0; p < 4; ++p) {
      int r = sa_rr + 32 * p;
      float4 v = *(const float4*)(X + (size_t)(row0 + r) * EM + k0 + sa_c4 * 4);
      int q = sa_c4 ^ ((r >> 3) & 7);
      *(float4*)(&As[r][q * 4]) = v;
    }
    // stage B tile (32x256) from wkT, XOR-swizzle quad by (quad>>3)&7
#pragma unroll
    for (int p = 0; p < 8; ++p) {
      int j = sb_j + 4 * p;
      float4 v = *(const float4*)(wkT + (size_t)(k0 + j) * EM + sb_c4 * 4);
      *(float4*)(&Bs[j][sb_off]) = v;
    }
    __syncthreads();

    for (int jq = 0; jq < 8; ++jq) {
      const int aoff = (jq ^ (ty & 7)) * 4;
      float4 a4[8];
#pragma unroll
      for (int i = 0; i < 8; ++i) a4[i] = *(const float4*)(&As[r0 + i][aoff]);
#pragma unroll
      for (int t = 0; t < 4; ++t) {
        const float* brow = &Bs[jq * 4 + t][0];
        float4 b0 = *(const float4*)(brow + bqoff[0]);
        float4 b1 = *(const float4*)(brow + bqoff[1]);
        float4 b2 = *(const float4*)(brow + bqoff[2]);
        float4 b3 = *(const float4*)(brow + bqoff[3]);
#pragma unroll
        for (int i = 0; i < 8; ++i) {
          float a = (t == 0) ? a4[i].x : (t == 1) ? a4[i].y : (t == 2) ? a4[i].z : a4[i].w;
          acc[i][0] = fmaf(a, b0.x, acc[i][0]);
          acc[i][1] = fmaf(a, b0.y, acc[i][1]);
          acc[i][2] = fmaf(a, b0.z, acc[i][2]);
          acc[i][3] = fmaf(a, b0.w, acc[i][3]);
          acc[i][4] = fmaf(a, b1.x, acc[i][4]);
          acc[i][5] = fmaf(a, b1.y, acc[i][5]);
          acc[i][6] = fmaf(a, b1.z, acc[i][6]);
          acc[i][7] = fmaf(a, b1.w, acc[i][7]);
          acc[i][8] = fmaf(a, b2.x, acc[i][8]);
          acc[i][9] = fmaf(a, b2.y, acc[i][9]);
          acc[i][10] = fmaf(a, b2.z, acc[i][10]);
          acc[i][11] = fmaf(a, b2.w, acc[i][11]);
          acc[i][12] = fmaf(a, b3.x, acc[i][12]);
          acc[i][13] = fmaf(a, b3.y, acc[i][13]);
          acc[i][14] = fmaf(a, b3.z, acc[i][14]);
          acc[i][15] = fmaf(a, b3.w, acc[i][15]);
        }
      }
    }
    __syncthreads();
  }

  // fused epilogue: bk, relu, tanh, dot we_k, reduce over the 16 tx lanes
  float pr[8];
#pragma unroll
  for (int i = 0; i < 8; ++i) pr[i] = 0.f;
#pragma unroll
  for (int c = 0; c < 16; ++c) {
    int e = e0 + c;
    float bkv = bk[e];
    float wev = we[EM + e];
#pragma unroll
    for (int i = 0; i < 8; ++i) {
      float v = fmaxf(acc[i][c] + bkv, 0.f);
      pr[i] += wev * tanhf(v);
    }
  }
#pragma unroll
  for (int i = 0; i < 8; ++i) {
    float p = pr[i];
#pragma unroll
    for (int off = 8; off >= 1; off >>= 1) p += __shfl_xor(p, off, 16);
    if (tx == 0) energy[row0 + r0 + i] = p;
  }
}

// ---- K2: per-batch masked softmax over SLEN ----
// Mask layout probe: lengths >= SLEN/2, so mask[0][1..3] are True. If the
// mask buffer is uint8, bytes 1..3 are nonzero; if int32, bytes 1..3 are the
// upper bytes of element 0 -> all zero. Uniform branch, both reads in-bounds.
__global__ __launch_bounds__(256) void k2_softmax(const float* __restrict__ energy,
                                                  const unsigned char* __restrict__ mask,
                                                  const float* __restrict__ cptr,
                                                  float* __restrict__ wout) {
  const int b = blockIdx.x;
  const int t = threadIdx.x;
  const float C = cptr[0];
  const bool mask_is_byte = (mask[1] | mask[2] | mask[3]) != 0;
  const int* mask32 = (const int*)mask;
  const float* eb = energy + (size_t)b * SLEN;
  float v[16];
  float m = -3.4e38f;
#pragma unroll
  for (int i = 0; i < 16; ++i) {
    int s = t + i * 256;
    int mv = mask_is_byte ? (int)mask[(size_t)b * SLEN + s]
                          : mask32[(size_t)b * SLEN + s];
    float x = mv ? (eb[s] + C) : 1.4012984643248171e-45f;  // jnp.float32(1e-45)
    v[i] = x;
    m = fmaxf(m, x);
  }
  __shared__ float red[8];
#pragma unroll
  for (int off = 32; off >= 1; off >>= 1) m = fmaxf(m, __shfl_xor(m, off, 64));
  if ((t & 63) == 0) red[t >> 6] = m;
  __syncthreads();
  m = fmaxf(fmaxf(red[0], red[1]), fmaxf(red[2], red[3]));
  float s_ = 0.f;
#pragma unroll
  for (int i = 0; i < 16; ++i) {
    v[i] = expf(v[i] - m);
    s_ += v[i];
  }
#pragma unroll
  for (int off = 32; off >= 1; off >>= 1) s_ += __shfl_xor(s_, off, 64);
  if ((t & 63) == 0) red[4 + (t >> 6)] = s_;
  __syncthreads();
  float inv = 1.f / (red[4] + red[5] + red[6] + red[7]);
  float* wb = wout + (size_t)b * SLEN;
#pragma unroll
  for (int i = 0; i < 16; ++i) wb[t + i * 256] = v[i] * inv;
}

// ---- K3: partial weighted sums. grid = 32 b x 16 chunks(256 s); 4 s-groups/block ----
__global__ __launch_bounds__(256) void k3_wsum(const float* __restrict__ X,
                                               const float* __restrict__ w,
                                               float* __restrict__ part) {
  const int b = blockIdx.x >> 4;
  const int ch = blockIdx.x & 15;
  const int g = threadIdx.x >> 6;   // 0..3 (s sub-group)
  const int l = threadIdx.x & 63;   // float4 slot over EM
  const int s0 = ch * 256 + g * 64;
  const float* xb = X + (size_t)b * SLEN * EM;
  const float* wb = w + (size_t)b * SLEN;
  float4 acc = make_float4(0.f, 0.f, 0.f, 0.f);
#pragma unroll 4
  for (int i = 0; i < 64; ++i) {
    int s = s0 + i;
    float ws_ = wb[s];
    float4 v = *(const float4*)(xb + (size_t)s * EM + l * 4);
    acc.x = fmaf(ws_, v.x, acc.x);
    acc.y = fmaf(ws_, v.y, acc.y);
    acc.z = fmaf(ws_, v.z, acc.z);
    acc.w = fmaf(ws_, v.w, acc.w);
  }
  *(float4*)(part + ((size_t)((b * 16 + ch) * 4 + g)) * EM + l * 4) = acc;
}

// ---- K4: reduce 64 partials per (b,e) -> out ----
__global__ __launch_bounds__(256) void k4_reduce(const float* __restrict__ part,
                                                 float* __restrict__ out) {
  const int b = blockIdx.x;
  const int e = threadIdx.x;
  float s = 0.f;
#pragma unroll 8
  for (int k = 0; k < 64; ++k) s += part[((size_t)b * 64 + k) * EM + e];
  out[(size_t)b * EM + e] = s;
}

extern "C" void kernel_launch(void* const* d_in, const int* in_sizes, int n_in,
                              void* d_out, int out_size, void* d_ws, size_t ws_size,
                              hipStream_t stream) {
  const float* X = (const float*)d_in[0];
  const unsigned char* mask = (const unsigned char*)d_in[1];  // probed byte-vs-int32 in k2
  const float* w_query = (const float*)d_in[2];
  const float* wq = (const float*)d_in[3];
  const float* bq = (const float*)d_in[4];
  const float* wk = (const float*)d_in[5];
  const float* bk = (const float*)d_in[6];
  const float* we = (const float*)d_in[7];
  const float* be = (const float*)d_in[8];
  float* out = (float*)d_out;
  float* ws = (float*)d_ws;

  float* wkT = ws + WS_WKT;
  float* energy = ws + WS_EN;
  float* cscalar = ws + WS_CONST;
  float* weights = ws + WS_W;
  float* part = ws + WS_PART;

  k0_transpose<<<64, 256, 0, stream>>>(wk, wkT);
  k0b_qscalar<<<1, 256, 0, stream>>>(w_query, wq, bq, we, be, cscalar);
  k1_energy<<<NROWS / 128, 256, 0, stream>>>(X, wkT, bk, we, energy);
  k2_softmax<<<BS, 256, 0, stream>>>(energy, mask, cscalar, weights);
  k3_wsum<<<BS * 16, 256, 0, stream>>>(X, weights, part);
  k4_reduce<<<BS, 256, 0, stream>>>(part, out);
}

// Round 3
// 292.110 us; speedup vs baseline: 1.7058x; 1.7058x over previous
//
#include <hip/hip_runtime.h>

#define BS   32
#define SLEN 4096
#define EM   256
#define NROWS (BS * SLEN)  // 131072

typedef __attribute__((ext_vector_type(8))) short bf16x8;
typedef __attribute__((ext_vector_type(4))) float f32x4;

// ---------------- ws layout (floats) ----------------
#define WS_WKB   0         // 32768  : wk as bf16 [e][j] (128KB)
#define WS_EN    32768     // 131072 : raw energy (tanh(k)@we_k)
#define WS_CONST 163840    // 16     : scalar energy_q + be
#define WS_W     163856    // 131072 : softmax weights
#define WS_PART  294928    // 524288 : wsum partials

__device__ inline short f2bf(float x) {
  union { float f; unsigned u; } v; v.f = x;
  unsigned r = v.u + 0x7fffu + ((v.u >> 16) & 1u);  // RNE
  return (short)(r >> 16);
}

#define GLOAD_LDS16(g, l)                                                  \
  __builtin_amdgcn_global_load_lds(                                        \
      (const __attribute__((address_space(1))) unsigned int*)(g),          \
      (__attribute__((address_space(3))) unsigned int*)(l), 16, 0, 0)

// ---- K0: convert wk (fp32 [e][j]) -> bf16 [e][j] ----
__global__ __launch_bounds__(256) void k0_cvt(const float* __restrict__ wk,
                                              unsigned short* __restrict__ wkb) {
  int idx = (blockIdx.x * 256 + threadIdx.x) * 4;
  float4 v = *(const float4*)(wk + idx);
  ushort4 o;
  o.x = (unsigned short)f2bf(v.x);
  o.y = (unsigned short)f2bf(v.y);
  o.z = (unsigned short)f2bf(v.z);
  o.w = (unsigned short)f2bf(v.w);
  *(ushort4*)(wkb + idx) = o;
}

// ---- K0b: scalar query path: C = tanh(relu(wq@w_query+bq)) . we_q + be ----
__global__ __launch_bounds__(256) void k0b_qscalar(const float* __restrict__ w_query,
                                                   const float* __restrict__ wq,
                                                   const float* __restrict__ bq,
                                                   const float* __restrict__ we,
                                                   const float* __restrict__ be,
                                                   float* __restrict__ outc) {
  int t = threadIdx.x;  // t = e
  float a = 0.f;
  const float* row = wq + (size_t)t * EM;
#pragma unroll 8
  for (int j = 0; j < EM; ++j) a = fmaf(row[j], w_query[j], a);
  a += bq[t];
  float v = we[t] * tanhf(fmaxf(a, 0.f));
#pragma unroll
  for (int off = 32; off >= 1; off >>= 1) v += __shfl_xor(v, off, 64);
  __shared__ float red[4];
  if ((t & 63) == 0) red[t >> 6] = v;
  __syncthreads();
  if (t == 0) outc[0] = red[0] + red[1] + red[2] + red[3] + be[0];
}

// ---- K1 (MFMA): energy[row] = sum_e we_k[e]*tanh(relu((X@wk^T)[row][e]+bk[e]))
// Block 256 thr = 4 waves, tile 64 rows x 256 cols, BK=64, 4 K-iters.
// Wave (wr,wc) owns rows wr*32+[0,32) x cols wc*128+[0,128): acc[2 rf][8 cf].
// LDS: As[64][64] bf16 (8KB) + Bs[256][64] bf16 (32KB), both rows 128B,
// chunk' = chunk ^ (row&7) XOR swizzle (T2). B staged via global_load_lds
// w=16 with pre-swizzled global source; A reg-staged fp32->bf16.
__global__ __launch_bounds__(256) void k1_energy(const float* __restrict__ X,
                                                 const unsigned short* __restrict__ wkb,
                                                 const float* __restrict__ bk,
                                                 const float* __restrict__ we,
                                                 float* __restrict__ energy) {
  __shared__ char lds[40960];
  char* As = lds;           // [64][64] bf16 swizzled
  char* Bs = lds + 8192;    // [256][64] bf16 swizzled
  const int tid = threadIdx.x;
  const int l = tid & 63;
  const int wid = tid >> 6;
  const int wr = wid >> 1, wc = wid & 1;
  const int row0 = blockIdx.x * 64;

  f32x4 acc[2][8];
#pragma unroll
  for (int i = 0; i < 2; ++i)
#pragma unroll
    for (int n = 0; n < 8; ++n) acc[i][n] = (f32x4){0.f, 0.f, 0.f, 0.f};

  // B gload: wave issues seg = wid*8+q; lane covers e = seg*8 + (l>>3),
  // LDS linear dest [e][l&7]; global chunk = (l&7) ^ (e&7), e&7 = l>>3.
  const int egl = l >> 3;
  const int cg = (l & 7) ^ egl;

  for (int it = 0; it < 4; ++it) {
    const int k0 = it * 64;
    // ---- stage B (32KB) via 8 global_load_lds per wave ----
#pragma unroll
    for (int q = 0; q < 8; ++q) {
      int seg = wid * 8 + q;
      int e = seg * 8 + egl;
      const char* g = (const char*)wkb + (size_t)e * 512 + k0 * 2 + cg * 16;
      GLOAD_LDS16(g, Bs + seg * 1024);
    }
    // ---- stage A (8KB): 2 chunks/thread, fp32->bf16, swizzled b128 write ----
#pragma unroll
    for (int p = 0; p < 2; ++p) {
      int n = tid + p * 256;
      int r = n >> 3, c = n & 7;
      const float* src = X + (size_t)(row0 + r) * EM + k0 + c * 8;
      float4 v0 = *(const float4*)(src);
      float4 v1 = *(const float4*)(src + 4);
      bf16x8 pk;
      pk[0] = f2bf(v0.x); pk[1] = f2bf(v0.y); pk[2] = f2bf(v0.z); pk[3] = f2bf(v0.w);
      pk[4] = f2bf(v1.x); pk[5] = f2bf(v1.y); pk[6] = f2bf(v1.z); pk[7] = f2bf(v1.w);
      *(bf16x8*)(As + r * 128 + ((c ^ (r & 7)) * 16)) = pk;
    }
    __syncthreads();
    // ---- compute: 2 k-steps x (2 rf x 8 cf) MFMA ----
#pragma unroll
    for (int s = 0; s < 2; ++s) {
      const int swz0 = ((s * 4 + (l >> 4)) ^ (l & 7)) * 16;
      bf16x8 af[2], bfr[8];
#pragma unroll
      for (int i = 0; i < 2; ++i) {
        int row = wr * 32 + i * 16 + (l & 15);
        af[i] = *(const bf16x8*)(As + row * 128 + swz0);
      }
#pragma unroll
      for (int n = 0; n < 8; ++n) {
        int e = wc * 128 + n * 16 + (l & 15);
        bfr[n] = *(const bf16x8*)(Bs + e * 128 + swz0);
      }
#pragma unroll
      for (int i = 0; i < 2; ++i)
#pragma unroll
        for (int n = 0; n < 8; ++n)
          acc[i][n] = __builtin_amdgcn_mfma_f32_16x16x32_bf16(af[i], bfr[n], acc[i][n], 0, 0, 0);
    }
    __syncthreads();
  }

  // ---- fused epilogue (fp32): bias, relu, tanh, dot we_k, row-reduce ----
  float bkv[8], wev[8];
#pragma unroll
  for (int n = 0; n < 8; ++n) {
    int e = wc * 128 + n * 16 + (l & 15);
    bkv[n] = bk[e];
    wev[n] = we[EM + e];
  }
  float* ep = (float*)lds;  // [64][2], safe: all waves past last barrier
#pragma unroll
  for (int i = 0; i < 2; ++i) {
#pragma unroll
    for (int r = 0; r < 4; ++r) {
      float p = 0.f;
#pragma unroll
      for (int n = 0; n < 8; ++n) {
        float kv = fmaxf(acc[i][n][r] + bkv[n], 0.f);
        p += wev[n] * tanhf(kv);
      }
#pragma unroll
      for (int off = 1; off <= 8; off <<= 1) p += __shfl_xor(p, off, 64);
      if ((l & 15) == 0) {
        int row_local = wr * 32 + i * 16 + (l >> 4) * 4 + r;
        ep[row_local * 2 + wc] = p;
      }
    }
  }
  __syncthreads();
  if (tid < 64) energy[row0 + tid] = ep[tid * 2] + ep[tid * 2 + 1];
}

// ---- K2: per-batch masked softmax over SLEN (byte-vs-int32 mask probe) ----
__global__ __launch_bounds__(256) void k2_softmax(const float* __restrict__ energy,
                                                  const unsigned char* __restrict__ mask,
                                                  const float* __restrict__ cptr,
                                                  float* __restrict__ wout) {
  const int b = blockIdx.x;
  const int t = threadIdx.x;
  const float C = cptr[0];
  const bool mask_is_byte = (mask[1] | mask[2] | mask[3]) != 0;
  const int* mask32 = (const int*)mask;
  const float* eb = energy + (size_t)b * SLEN;
  float v[16];
  float m = -3.4e38f;
#pragma unroll
  for (int i = 0; i < 16; ++i) {
    int s = t + i * 256;
    int mv = mask_is_byte ? (int)mask[(size_t)b * SLEN + s]
                          : mask32[(size_t)b * SLEN + s];
    float x = mv ? (eb[s] + C) : 1.4012984643248171e-45f;
    v[i] = x;
    m = fmaxf(m, x);
  }
  __shared__ float red[8];
#pragma unroll
  for (int off = 32; off >= 1; off >>= 1) m = fmaxf(m, __shfl_xor(m, off, 64));
  if ((t & 63) == 0) red[t >> 6] = m;
  __syncthreads();
  m = fmaxf(fmaxf(red[0], red[1]), fmaxf(red[2], red[3]));
  float s_ = 0.f;
#pragma unroll
  for (int i = 0; i < 16; ++i) {
    v[i] = expf(v[i] - m);
    s_ += v[i];
  }
#pragma unroll
  for (int off = 32; off >= 1; off >>= 1) s_ += __shfl_xor(s_, off, 64);
  if ((t & 63) == 0) red[4 + (t >> 6)] = s_;
  __syncthreads();
  float inv = 1.f / (red[4] + red[5] + red[6] + red[7]);
  float* wb = wout + (size_t)b * SLEN;
#pragma unroll
  for (int i = 0; i < 16; ++i) wb[t + i * 256] = v[i] * inv;
}

// ---- K3: partial weighted sums ----
__global__ __launch_bounds__(256) void k3_wsum(const float* __restrict__ X,
                                               const float* __restrict__ w,
                                               float* __restrict__ part) {
  const int b = blockIdx.x >> 4;
  const int ch = blockIdx.x & 15;
  const int g = threadIdx.x >> 6;
  const int l = threadIdx.x & 63;
  const int s0 = ch * 256 + g * 64;
  const float* xb = X + (size_t)b * SLEN * EM;
  const float* wb = w + (size_t)b * SLEN;
  float4 acc = make_float4(0.f, 0.f, 0.f, 0.f);
#pragma unroll 4
  for (int i = 0; i < 64; ++i) {
    int s = s0 + i;
    float ws_ = wb[s];
    float4 v = *(const float4*)(xb + (size_t)s * EM + l * 4);
    acc.x = fmaf(ws_, v.x, acc.x);
    acc.y = fmaf(ws_, v.y, acc.y);
    acc.z = fmaf(ws_, v.z, acc.z);
    acc.w = fmaf(ws_, v.w, acc.w);
  }
  *(float4*)(part + ((size_t)((b * 16 + ch) * 4 + g)) * EM + l * 4) = acc;
}

// ---- K4: reduce 64 partials per (b,e) -> out ----
__global__ __launch_bounds__(256) void k4_reduce(const float* __restrict__ part,
                                                 float* __restrict__ out) {
  const int b = blockIdx.x;
  const int e = threadIdx.x;
  float s = 0.f;
#pragma unroll 8
  for (int k = 0; k < 64; ++k) s += part[((size_t)b * 64 + k) * EM + e];
  out[(size_t)b * EM + e] = s;
}

extern "C" void kernel_launch(void* const* d_in, const int* in_sizes, int n_in,
                              void* d_out, int out_size, void* d_ws, size_t ws_size,
                              hipStream_t stream) {
  const float* X = (const float*)d_in[0];
  const unsigned char* mask = (const unsigned char*)d_in[1];
  const float* w_query = (const float*)d_in[2];
  const float* wq = (const float*)d_in[3];
  const float* bq = (const float*)d_in[4];
  const float* wk = (const float*)d_in[5];
  const float* bk = (const float*)d_in[6];
  const float* we = (const float*)d_in[7];
  const float* be = (const float*)d_in[8];
  float* out = (float*)d_out;
  float* ws = (float*)d_ws;

  unsigned short* wkb = (unsigned short*)(ws + WS_WKB);
  float* energy = ws + WS_EN;
  float* cscalar = ws + WS_CONST;
  float* weights = ws + WS_W;
  float* part = ws + WS_PART;

  k0_cvt<<<64, 256, 0, stream>>>(wk, wkb);
  k0b_qscalar<<<1, 256, 0, stream>>>(w_query, wq, bq, we, be, cscalar);
  k1_energy<<<NROWS / 64, 256, 0, stream>>>(X, wkb, bk, we, energy);
  k2_softmax<<<BS, 256, 0, stream>>>(energy, mask, cscalar, weights);
  k3_wsum<<<BS * 16, 256, 0, stream>>>(X, weights, part);
  k4_reduce<<<BS, 256, 0, stream>>>(part, out);
}